// Round 3
// baseline (930.473 us; speedup 1.0000x reference)
//
#include <hip/hip_runtime.h>
#include <float.h>

// Problem shape (fixed by setup_inputs): x[32768,512], embed[4096,512]
#define D 512
#define NPTS 32768
#define KCODES 4096
#define EPSV 1e-6f

typedef __attribute__((ext_vector_type(8))) short short8;
typedef __attribute__((ext_vector_type(4))) float f32x4;
typedef unsigned short u16;
typedef __attribute__((ext_vector_type(8))) unsigned short u16x8;

// ---------------------------------------------------------------------------
// async global->LDS, 16B per lane (dest = wave-uniform base + lane*16)
__device__ __forceinline__ void async16(void* lds, const void* gl) {
    __builtin_amdgcn_global_load_lds(
        (const __attribute__((address_space(1))) unsigned int*)gl,
        (__attribute__((address_space(3))) unsigned int*)lds,
        16, 0, 0);
}

// fp32 -> bf16 round-to-nearest-even
__device__ __forceinline__ unsigned short f2bf(float f) {
    unsigned int u = __float_as_uint(f);
    u += 0x7fffu + ((u >> 16) & 1u);
    return (unsigned short)(u >> 16);
}

__global__ void cvt_bf16_kernel(const float* __restrict__ in, u16* __restrict__ out) {
    size_t i = (size_t)(blockIdx.x * 256 + threadIdx.x) * 8;
    float4 a = *(const float4*)(in + i);
    float4 b = *(const float4*)(in + i + 4);
    u16x8 r = { f2bf(a.x), f2bf(a.y), f2bf(a.z), f2bf(a.w),
                f2bf(b.x), f2bf(b.y), f2bf(b.z), f2bf(b.w) };
    *(u16x8*)(out + i) = r;
}

// ---------------------------------------------------------------------------
// Bit-exact emulation of numpy fp32 pairwise sum of squares over a 512-row.
// (verified passing — do not change)
__device__ __forceinline__ float np_sumsq_512(const float* __restrict__ row, int l) {
    int b = l >> 3, j = l & 7;
    int base = b * 128 + j;
    float a = row[base];
    float r = __fmul_rn(a, a);
#pragma unroll
    for (int t = 1; t < 16; ++t) {
        float v = row[base + 8 * t];
        r = __fadd_rn(r, __fmul_rn(v, v));
    }
#pragma unroll
    for (int off = 1; off <= 16; off <<= 1)
        r = __fadd_rn(r, __shfl_xor(r, off));
    return r;
}

__global__ void xx_np_kernel(const float* __restrict__ x, float* __restrict__ xx_np) {
    int w = threadIdx.x >> 6, lane = threadIdx.x & 63;
    int hf = lane >> 5, l = lane & 31;
    int p = blockIdx.x * 8 + w * 2 + hf;
    float r = np_sumsq_512(x + (size_t)p * D, l);
    if (l == 0) xx_np[p] = r;
}

__global__ void ee_np_kernel(const float* __restrict__ emb, float* __restrict__ ee_np) {
    int w = threadIdx.x >> 6, lane = threadIdx.x & 63;
    int hf = lane >> 5, l = lane & 31;
    int k = blockIdx.x * 8 + w * 2 + hf;
    float r = np_sumsq_512(emb + (size_t)k * D, l);
    if (l == 0) ee_np[k] = r;
}

// ---------------------------------------------------------------------------
// fused EMA inits (one launch): nea = ea*decay over K*D; ncs = cs*decay over K
__global__ void init_kernel(const float* __restrict__ cs, const float* __restrict__ ea,
                            const float* __restrict__ decay_p,
                            float* __restrict__ ncs, float* __restrict__ nea) {
    int i = blockIdx.x * 256 + threadIdx.x;
    float dv = decay_p[0];
    nea[i] = ea[i] * dv;
    if (i < KCODES) ncs[i] = cs[i] * dv;
}

// ---------------------------------------------------------------------------
// bf16 MFMA screen: scores s[n][k] = ee[k] - 2*dot(x_n, e_k).
// Grid (NPTS/128, 4): each block = 128 pts x 1024 codes (one code-quarter),
// 8 chunks of 128 codes; emits approx-top-4 (exact top-2) per (point, quarter)
// into 16-slot scr16/idx16 (same emit network as the verified half/top-4
// config, applied per quarter -> weakly stronger candidate coverage).
// K-loop: double-buffered LDS, single raw s_barrier + vmcnt(0) per BK=32 step
// (T3 minimum 2-phase: stage next step's tiles before the MFMA cluster of the
// current step so global_load_lds is in flight under compute).
// LDS chunk-XOR-swizzle p = kc ^ ((row>>2)&3) keeps frag ds_read_b128
// 2-way-per-bank (free, m136).
#define INS4(s_, c_)  do {                                                  \
    bool l0 = (s_) < m0, l1 = (s_) < m1, l2 = (s_) < m2, l3 = (s_) < m3;    \
    m3 = l2 ? m2 : (l3 ? (s_) : m3);  q3 = l2 ? q2 : (l3 ? (c_) : q3);      \
    m2 = l1 ? m1 : (l2 ? (s_) : m2);  q2 = l1 ? q1 : (l2 ? (c_) : q2);      \
    m1 = l0 ? m0 : (l1 ? (s_) : m1);  q1 = l0 ? q0 : (l1 ? (c_) : q1);      \
    m0 = l0 ? (s_) : m0;              q0 = l0 ? (c_) : q0;                  \
} while (0)

__global__ __launch_bounds__(256, 4)
void screen_kernel(const u16* __restrict__ xb, const u16* __restrict__ eb,
                   const float* __restrict__ ee,
                   float* __restrict__ scr16, int* __restrict__ idx16) {
    // [parity][A/B][128 rows * 32 k] bf16, 32 KiB total; reduction arrays
    // alias this space after the K loops (buffers dead by then).
    __shared__ __align__(16) u16 S[2][2][128 * 32];

    const int tid = threadIdx.x;
    const int w = tid >> 6, lane = tid & 63;
    const int wy = w >> 1, wx = w & 1;
    const int tx = lane & 15, g = lane >> 4;
    const int n0 = blockIdx.x * 128;
    const int hf = blockIdx.y;                 // code quarter 0..3
    const int hbase = hf * 1024;

    // per-lane running top-2 per row-slot (fi*4+r)
    float v1[16], v2[16];
    int   i1[16], i2[16];
#pragma unroll
    for (int s = 0; s < 16; ++s) { v1[s] = FLT_MAX; v2[s] = FLT_MAX; i1[s] = 0; i2[s] = 0; }

    // staging lane constants: instr t covers rows [16t,16t+16); lane l ->
    // row 16t+(l>>2), physical 16B-chunk l&3 holds logical chunk (l&3)^(l>>4)
    const int kc = (lane & 3) ^ (lane >> 4);
    const int srow = lane >> 2;
    const int ta = 2 * w, tb = 2 * w + 1;
    const size_t aoa = (size_t)(n0 + 16 * ta + srow) * D + kc * 8;
    const size_t aob = (size_t)(n0 + 16 * tb + srow) * D + kc * 8;
    const size_t boa = (size_t)(hbase + 16 * ta + srow) * D + kc * 8;
    const size_t bob = (size_t)(hbase + 16 * tb + srow) * D + kc * 8;

    auto stage = [&](int s, int p) {
        const int ch = s >> 4;
        const size_t ko = (size_t)((s & 15) * 32);
        const size_t co = (size_t)ch * (128 * D);
        async16(&S[p][0][ta * 512], xb + aoa + ko);
        async16(&S[p][0][tb * 512], xb + aob + ko);
        async16(&S[p][1][ta * 512], eb + boa + co + ko);
        async16(&S[p][1][tb * 512], eb + bob + co + ko);
    };

    // prologue: fill buffer 0
    stage(0, 0);
    asm volatile("s_waitcnt vmcnt(0)" ::: "memory");
    __builtin_amdgcn_s_barrier();

    for (int c = 0; c < 8; ++c) {
        const int c0 = hbase + c * 128;
        // preload ee for this chunk (register-resident by the epilogue use)
        float eev[4];
#pragma unroll
        for (int fj = 0; fj < 4; ++fj) eev[fj] = ee[c0 + wx * 64 + 16 * fj + tx];

        f32x4 acc[4][4];
#pragma unroll
        for (int fi = 0; fi < 4; ++fi)
#pragma unroll
            for (int fj = 0; fj < 4; ++fj) acc[fi][fj] = (f32x4){0.f, 0.f, 0.f, 0.f};

        for (int kk = 0; kk < 16; ++kk) {
            const int s = c * 16 + kk;
            const int par = s & 1;
            const u16* Ab = &S[par][0][0];
            const u16* Bb = &S[par][1][0];

            // ds_read current buffer (completed: prior step's vmcnt(0)+barrier)
            short8 af[4], bf[4];
#pragma unroll
            for (int fi = 0; fi < 4; ++fi) {
                int row = wy * 64 + 16 * fi + tx;
                int ph = g ^ ((row >> 2) & 3);
                af[fi] = *(const short8*)&Ab[row * 32 + ph * 8];
            }
#pragma unroll
            for (int fj = 0; fj < 4; ++fj) {
                int row = wx * 64 + 16 * fj + tx;
                int ph = g ^ ((row >> 2) & 3);
                bf[fj] = *(const short8*)&Bb[row * 32 + ph * 8];
            }

            // issue next step's staging into the other buffer; its loads stay
            // in flight under the MFMA cluster below.
            if (s < 127) stage(s + 1, par ^ 1);

#pragma unroll
            for (int fi = 0; fi < 4; ++fi)
#pragma unroll
                for (int fj = 0; fj < 4; ++fj)
                    acc[fi][fj] = __builtin_amdgcn_mfma_f32_16x16x32_bf16(
                        af[fi], bf[fj], acc[fi][fj], 0, 0, 0);

            if (kk == 15) {
                // chunk epilogue: fold scores into per-lane top-2 (register-only
                // + preloaded eev) — more latency cover for in-flight staging.
#pragma unroll
                for (int fj = 0; fj < 4; ++fj) {
                    int col = c0 + wx * 64 + 16 * fj + tx;
                    float ev = eev[fj];
#pragma unroll
                    for (int fi = 0; fi < 4; ++fi)
#pragma unroll
                        for (int r = 0; r < 4; ++r) {
                            float sc = fmaf(-2.0f, acc[fi][fj][r], ev);
                            const int slot = fi * 4 + r;
                            bool b1 = sc < v1[slot];
                            bool b2 = sc < v2[slot];
                            float ov = v1[slot]; int oi = i1[slot];
                            v1[slot] = b1 ? sc : ov;
                            i1[slot] = b1 ? col : oi;
                            v2[slot] = b1 ? ov : (b2 ? sc : v2[slot]);
                            i2[slot] = b1 ? oi : (b2 ? col : i2[slot]);
                        }
                }
            }

            // single drain+barrier per step: next buffer staged by all waves,
            // and all waves' frag reads of this buffer are done.
            asm volatile("s_waitcnt vmcnt(0)" ::: "memory");
            __builtin_amdgcn_s_barrier();
        }
    }

    // cross-lane: per row, approx-top-4 (exact top-2) over the wave's 64 cols.
    // Reduction arrays alias dead tile LDS (4 KiB each, within S's 32 KiB).
    float (*s_scr)[2][4] = reinterpret_cast<float (*)[2][4]>(&S[0][0][0]);
    int   (*s_idx)[2][4] = reinterpret_cast<int (*)[2][4]>(&S[0][1][0]);

#pragma unroll
    for (int fi = 0; fi < 4; ++fi) {
#pragma unroll
        for (int r = 0; r < 4; ++r) {
            const int slot = fi * 4 + r;
            float m0 = v1[slot], m1 = v2[slot], m2 = FLT_MAX, m3 = FLT_MAX;
            int   q0 = i1[slot], q1 = i2[slot], q2 = 0, q3 = 0;
#pragma unroll
            for (int off = 1; off <= 8; off <<= 1) {
                float o0 = __shfl_xor(m0, off), o1 = __shfl_xor(m1, off);
                float o2 = __shfl_xor(m2, off), o3 = __shfl_xor(m3, off);
                int   p0 = __shfl_xor(q0, off), p1 = __shfl_xor(q1, off);
                int   p2 = __shfl_xor(q2, off), p3 = __shfl_xor(q3, off);
                INS4(o0, p0); INS4(o1, p1); INS4(o2, p2); INS4(o3, p3);
            }
            if (tx == 0) {
                int row = wy * 64 + 16 * fi + 4 * g + r;
                s_scr[row][wx][0] = m0; s_scr[row][wx][1] = m1;
                s_scr[row][wx][2] = m2; s_scr[row][wx][3] = m3;
                s_idx[row][wx][0] = q0; s_idx[row][wx][1] = q1;
                s_idx[row][wx][2] = q2; s_idx[row][wx][3] = q3;
            }
        }
    }
    __syncthreads();
    if (tid < 128) {
        float m0 = s_scr[tid][0][0], m1 = s_scr[tid][0][1],
              m2 = s_scr[tid][0][2], m3 = s_scr[tid][0][3];
        int   q0 = s_idx[tid][0][0], q1 = s_idx[tid][0][1],
              q2 = s_idx[tid][0][2], q3 = s_idx[tid][0][3];
#pragma unroll
        for (int q = 0; q < 4; ++q) INS4(s_scr[tid][1][q], s_idx[tid][1][q]);
        int pt = n0 + tid;
        scr16[(hf * 4 + 0) * NPTS + pt] = m0; idx16[(hf * 4 + 0) * NPTS + pt] = q0;
        scr16[(hf * 4 + 1) * NPTS + pt] = m1; idx16[(hf * 4 + 1) * NPTS + pt] = q1;
        scr16[(hf * 4 + 2) * NPTS + pt] = m2; idx16[(hf * 4 + 2) * NPTS + pt] = q2;
        scr16[(hf * 4 + 3) * NPTS + pt] = m3; idx16[(hf * 4 + 3) * NPTS + pt] = q3;
    }
}

// ---------------------------------------------------------------------------
// merge the four quarters' top-4 into global screen top-4 per point
__global__ void merge16_kernel(const float* __restrict__ scr16, const int* __restrict__ idx16,
                               int* __restrict__ cand) {
    int n = blockIdx.x * 256 + threadIdx.x;
    float m0 = FLT_MAX, m1 = FLT_MAX, m2 = FLT_MAX, m3 = FLT_MAX;
    int   q0 = 0, q1 = 0, q2 = 0, q3 = 0;
#pragma unroll
    for (int c = 0; c < 16; ++c) {
        float s = scr16[c * NPTS + n];
        int   i = idx16[c * NPTS + n];
        INS4(s, i);
    }
    cand[0 * NPTS + n] = q0; cand[1 * NPTS + n] = q1;
    cand[2 * NPTS + n] = q2; cand[3 * NPTS + n] = q3;
}

// ---------------------------------------------------------------------------
// Final selection emulating numpy fp32 (verified passing — unchanged)
__global__ void rescore_kernel(const float* __restrict__ x, const float* __restrict__ emb,
                               const int* __restrict__ cand,
                               const float* __restrict__ xx_np,
                               const float* __restrict__ ee_np,
                               float* __restrict__ ind_f,
                               float* __restrict__ ncs, const float* __restrict__ decay_p) {
    int w = threadIdx.x >> 6, lane = threadIdx.x & 63;
    int n = blockIdx.x * 4 + w;
    float xxv = xx_np[n];
    float bestd = FLT_MAX; int bidx = 0x7fffffff;
#pragma unroll
    for (int c = 0; c < 4; ++c) {
        int k = cand[c * NPTS + n];
        double acc = 0.0;
#pragma unroll
        for (int i = 0; i < 8; ++i) {
            int d = lane + i * 64;
            acc += (double)emb[(size_t)k * D + d] * (double)x[(size_t)n * D + d];
        }
#pragma unroll
        for (int off = 32; off >= 1; off >>= 1) acc += __shfl_xor(acc, off);
        float mf = (float)acc;
        float t  = __fmul_rn(2.0f, mf);
        float u  = __fsub_rn(xxv, t);
        float dd = __fadd_rn(u, ee_np[k]);
        if (dd < bestd || (dd == bestd && k < bidx)) { bestd = dd; bidx = k; }
    }
    if (lane == 0) {
        ind_f[n] = (float)bidx;
        atomicAdd(&ncs[bidx], 1.0f - decay_p[0]);
    }
}

// ---------------------------------------------------------------------------
__global__ void gather_scatter_kernel(const float* __restrict__ x,
                                      const float* __restrict__ emb,
                                      const float* __restrict__ ind_f,
                                      float* __restrict__ quant, float* __restrict__ nea,
                                      const float* __restrict__ decay_p) {
    int gid = blockIdx.x * 256 + threadIdx.x;   // NPTS * (D/4)
    int n = gid >> 7, dq = gid & 127;
    int k = (int)ind_f[n];
    float4 e4 = *(const float4*)(emb + (size_t)k * D + dq * 4);
    *(float4*)(quant + (size_t)n * D + dq * 4) = e4;
    float4 x4 = *(const float4*)(x + (size_t)n * D + dq * 4);
    float wgt = 1.0f - decay_p[0];
    float* base = nea + (size_t)k * D + dq * 4;
    atomicAdd(base + 0, x4.x * wgt);
    atomicAdd(base + 1, x4.y * wgt);
    atomicAdd(base + 2, x4.z * wgt);
    atomicAdd(base + 3, x4.w * wgt);
}

// ---------------------------------------------------------------------------
__global__ void total_kernel(const float* __restrict__ ncs, float* __restrict__ total) {
    __shared__ float sd[1024];
    int t = threadIdx.x;
    sd[t] = ncs[t] + ncs[t + 1024] + ncs[t + 2048] + ncs[t + 3072];
    __syncthreads();
    for (int st = 512; st > 0; st >>= 1) {
        if (t < st) sd[t] += sd[t + st];
        __syncthreads();
    }
    if (t == 0) total[0] = sd[0];
}

__global__ void new_embed_kernel(const float* __restrict__ nea, const float* __restrict__ ncs,
                                 const float* __restrict__ total, float* __restrict__ ne) {
    int i = blockIdx.x * 256 + threadIdx.x;   // K*D
    int k = i >> 9;
    float t = total[0];
    float sm = (ncs[k] + EPSV) / (t + EPSV * (float)KCODES) * t;
    ne[i] = nea[i] / sm;
}

// ---------------------------------------------------------------------------
extern "C" void kernel_launch(void* const* d_in, const int* in_sizes, int n_in,
                              void* d_out, int out_size, void* d_ws, size_t ws_size,
                              hipStream_t stream) {
    const float* x     = (const float*)d_in[0];
    const float* emb   = (const float*)d_in[1];
    const float* cs    = (const float*)d_in[2];
    const float* ea    = (const float*)d_in[3];
    const float* decay = (const float*)d_in[4];

    float* out   = (float*)d_out;
    float* quant = out;                               // NPTS*D
    float* ind_f = out + (size_t)NPTS * D;            // NPTS
    float* ncs   = ind_f + NPTS;                      // KCODES
    float* nea   = ncs + KCODES;                      // KCODES*D
    float* ne    = nea + (size_t)KCODES * D;          // KCODES*D

    float* ws    = (float*)d_ws;
    float* ee_np = ws;                                // KCODES
    float* xx_np = ws + KCODES;                       // NPTS
    float* scr16 = xx_np + NPTS;                      // 16*NPTS
    int*   idx16 = (int*)(scr16 + 16 * (size_t)NPTS); // 16*NPTS
    int*   cand  = idx16 + 16 * (size_t)NPTS;         // 4*NPTS
    u16*   eb    = (u16*)(cand + 4 * (size_t)NPTS);   // KCODES*D bf16 (16B-aligned)
    float* total = (float*)(eb + (size_t)KCODES * D); // 1

    // bf16 x staged in the quant output region (overwritten at the end)
    u16* xb = (u16*)quant;

    hipLaunchKernelGGL(cvt_bf16_kernel, dim3(NPTS * D / 2048),   dim3(256), 0, stream, x, xb);
    hipLaunchKernelGGL(cvt_bf16_kernel, dim3(KCODES * D / 2048), dim3(256), 0, stream, emb, eb);
    hipLaunchKernelGGL(ee_np_kernel,    dim3(KCODES / 8),        dim3(256), 0, stream, emb, ee_np);
    hipLaunchKernelGGL(xx_np_kernel,    dim3(NPTS / 8),          dim3(256), 0, stream, x, xx_np);
    hipLaunchKernelGGL(init_kernel,     dim3(KCODES * (D / 256)), dim3(256), 0, stream, cs, ea, decay, ncs, nea);
    hipLaunchKernelGGL(screen_kernel,   dim3(NPTS / 128, 4),     dim3(256), 0, stream,
                       xb, eb, ee_np, scr16, idx16);
    hipLaunchKernelGGL(merge16_kernel,  dim3(NPTS / 256),        dim3(256), 0, stream, scr16, idx16, cand);
    hipLaunchKernelGGL(rescore_kernel,  dim3(NPTS / 4),          dim3(256), 0, stream,
                       x, emb, cand, xx_np, ee_np, ind_f, ncs, decay);
    hipLaunchKernelGGL(gather_scatter_kernel, dim3(NPTS * (D / 4) / 256), dim3(256), 0, stream,
                       x, emb, ind_f, quant, nea, decay);
    hipLaunchKernelGGL(total_kernel,    dim3(1),                 dim3(1024), 0, stream, ncs, total);
    hipLaunchKernelGGL(new_embed_kernel, dim3(KCODES * (D / 256)), dim3(256), 0, stream, nea, ncs, total, ne);
}

// Round 4
// 723.269 us; speedup vs baseline: 1.2865x; 1.2865x over previous
//
#include <hip/hip_runtime.h>
#include <float.h>

// Problem shape (fixed by setup_inputs): x[32768,512], embed[4096,512]
#define D 512
#define NPTS 32768
#define KCODES 4096
#define EPSV 1e-6f

typedef __attribute__((ext_vector_type(8))) short short8;
typedef __attribute__((ext_vector_type(4))) float f32x4;
typedef unsigned short u16;
typedef __attribute__((ext_vector_type(8))) unsigned short u16x8;

// ---------------------------------------------------------------------------
// async global->LDS, 16B per lane (dest = wave-uniform base + lane*16)
__device__ __forceinline__ void async16(void* lds, const void* gl) {
    __builtin_amdgcn_global_load_lds(
        (const __attribute__((address_space(1))) unsigned int*)gl,
        (__attribute__((address_space(3))) unsigned int*)lds,
        16, 0, 0);
}

// fp32 -> bf16 round-to-nearest-even
__device__ __forceinline__ unsigned short f2bf(float f) {
    unsigned int u = __float_as_uint(f);
    u += 0x7fffu + ((u >> 16) & 1u);
    return (unsigned short)(u >> 16);
}

__global__ void cvt_bf16_kernel(const float* __restrict__ in, u16* __restrict__ out) {
    size_t i = (size_t)(blockIdx.x * 256 + threadIdx.x) * 8;
    float4 a = *(const float4*)(in + i);
    float4 b = *(const float4*)(in + i + 4);
    u16x8 r = { f2bf(a.x), f2bf(a.y), f2bf(a.z), f2bf(a.w),
                f2bf(b.x), f2bf(b.y), f2bf(b.z), f2bf(b.w) };
    *(u16x8*)(out + i) = r;
}

// ---------------------------------------------------------------------------
// Bit-exact emulation of numpy fp32 pairwise sum of squares over a 512-row.
// (verified passing — do not change)
__device__ __forceinline__ float np_sumsq_512(const float* __restrict__ row, int l) {
    int b = l >> 3, j = l & 7;
    int base = b * 128 + j;
    float a = row[base];
    float r = __fmul_rn(a, a);
#pragma unroll
    for (int t = 1; t < 16; ++t) {
        float v = row[base + 8 * t];
        r = __fadd_rn(r, __fmul_rn(v, v));
    }
#pragma unroll
    for (int off = 1; off <= 16; off <<= 1)
        r = __fadd_rn(r, __shfl_xor(r, off));
    return r;
}

__global__ void xx_np_kernel(const float* __restrict__ x, float* __restrict__ xx_np) {
    int w = threadIdx.x >> 6, lane = threadIdx.x & 63;
    int hf = lane >> 5, l = lane & 31;
    int p = blockIdx.x * 8 + w * 2 + hf;
    float r = np_sumsq_512(x + (size_t)p * D, l);
    if (l == 0) xx_np[p] = r;
}

__global__ void ee_np_kernel(const float* __restrict__ emb, float* __restrict__ ee_np) {
    int w = threadIdx.x >> 6, lane = threadIdx.x & 63;
    int hf = lane >> 5, l = lane & 31;
    int k = blockIdx.x * 8 + w * 2 + hf;
    float r = np_sumsq_512(emb + (size_t)k * D, l);
    if (l == 0) ee_np[k] = r;
}

// ---------------------------------------------------------------------------
// fused EMA inits (one launch): nea = ea*decay over K*D; ncs = cs*decay over K
__global__ void init_kernel(const float* __restrict__ cs, const float* __restrict__ ea,
                            const float* __restrict__ decay_p,
                            float* __restrict__ ncs, float* __restrict__ nea) {
    int i = blockIdx.x * 256 + threadIdx.x;
    float dv = decay_p[0];
    nea[i] = ea[i] * dv;
    if (i < KCODES) ncs[i] = cs[i] * dv;
}

// ---------------------------------------------------------------------------
// bf16 MFMA screen: scores s[n][k] = ee[k] - 2*dot(x_n, e_k).
// Grid (NPTS/128, 4): each block = 128 pts x 1024 codes (one code-quarter),
// 8 chunks of 128 codes; emits approx-top-4 (exact top-2) per (point, quarter)
// into 16-slot scr16/idx16 (same emit network as the verified half/top-4
// config, applied per quarter -> weakly stronger candidate coverage).
// K-loop: double-buffered LDS, single raw s_barrier + vmcnt(0) per BK=32 step
// (T3 minimum 2-phase: stage next step's tiles before the MFMA cluster of the
// current step so global_load_lds is in flight under compute).
// LDS chunk-XOR-swizzle p = kc ^ ((row>>2)&3) keeps frag ds_read_b128
// 2-way-per-bank (free, m136).
// __launch_bounds__(256, 2): the kernel's live state is ~192 regs/wave
// (64 AGPR acc + ~128 VGPR); forcing 4 blocks/CU (round 3) spilled to
// scratch (WRITE_SIZE 5.6MB -> 728MB, MfmaUtil halved). 2 waves/EU budget
// (256 regs) keeps it spill-free; the 2-phase pipeline must earn its win
// at 2 blocks/CU.
#define INS4(s_, c_)  do {                                                  \
    bool l0 = (s_) < m0, l1 = (s_) < m1, l2 = (s_) < m2, l3 = (s_) < m3;    \
    m3 = l2 ? m2 : (l3 ? (s_) : m3);  q3 = l2 ? q2 : (l3 ? (c_) : q3);      \
    m2 = l1 ? m1 : (l2 ? (s_) : m2);  q2 = l1 ? q1 : (l2 ? (c_) : q2);      \
    m1 = l0 ? m0 : (l1 ? (s_) : m1);  q1 = l0 ? q0 : (l1 ? (c_) : q1);      \
    m0 = l0 ? (s_) : m0;              q0 = l0 ? (c_) : q0;                  \
} while (0)

__global__ __launch_bounds__(256, 2)
void screen_kernel(const u16* __restrict__ xb, const u16* __restrict__ eb,
                   const float* __restrict__ ee,
                   float* __restrict__ scr16, int* __restrict__ idx16) {
    // [parity][A/B][128 rows * 32 k] bf16, 32 KiB total; reduction arrays
    // alias this space after the K loops (buffers dead by then).
    __shared__ __align__(16) u16 S[2][2][128 * 32];

    const int tid = threadIdx.x;
    const int w = tid >> 6, lane = tid & 63;
    const int wy = w >> 1, wx = w & 1;
    const int tx = lane & 15, g = lane >> 4;
    const int n0 = blockIdx.x * 128;
    const int hf = blockIdx.y;                 // code quarter 0..3
    const int hbase = hf * 1024;

    // per-lane running top-2 per row-slot (fi*4+r)
    float v1[16], v2[16];
    int   i1[16], i2[16];
#pragma unroll
    for (int s = 0; s < 16; ++s) { v1[s] = FLT_MAX; v2[s] = FLT_MAX; i1[s] = 0; i2[s] = 0; }

    // staging lane constants: instr t covers rows [16t,16t+16); lane l ->
    // row 16t+(l>>2), physical 16B-chunk l&3 holds logical chunk (l&3)^(l>>4)
    const int kc = (lane & 3) ^ (lane >> 4);
    const int srow = lane >> 2;
    const int ta = 2 * w, tb = 2 * w + 1;
    const size_t aoa = (size_t)(n0 + 16 * ta + srow) * D + kc * 8;
    const size_t aob = (size_t)(n0 + 16 * tb + srow) * D + kc * 8;
    const size_t boa = (size_t)(hbase + 16 * ta + srow) * D + kc * 8;
    const size_t bob = (size_t)(hbase + 16 * tb + srow) * D + kc * 8;

    auto stage = [&](int s, int p) {
        const int ch = s >> 4;
        const size_t ko = (size_t)((s & 15) * 32);
        const size_t co = (size_t)ch * (128 * D);
        async16(&S[p][0][ta * 512], xb + aoa + ko);
        async16(&S[p][0][tb * 512], xb + aob + ko);
        async16(&S[p][1][ta * 512], eb + boa + co + ko);
        async16(&S[p][1][tb * 512], eb + bob + co + ko);
    };

    // prologue: fill buffer 0
    stage(0, 0);
    asm volatile("s_waitcnt vmcnt(0)" ::: "memory");
    __builtin_amdgcn_s_barrier();

    for (int c = 0; c < 8; ++c) {
        const int c0 = hbase + c * 128;
        // preload ee for this chunk (register-resident by the epilogue use)
        float eev[4];
#pragma unroll
        for (int fj = 0; fj < 4; ++fj) eev[fj] = ee[c0 + wx * 64 + 16 * fj + tx];

        f32x4 acc[4][4];
#pragma unroll
        for (int fi = 0; fi < 4; ++fi)
#pragma unroll
            for (int fj = 0; fj < 4; ++fj) acc[fi][fj] = (f32x4){0.f, 0.f, 0.f, 0.f};

        for (int kk = 0; kk < 16; ++kk) {
            const int s = c * 16 + kk;
            const int par = s & 1;
            const u16* Ab = &S[par][0][0];
            const u16* Bb = &S[par][1][0];

            // ds_read current buffer (completed: prior step's vmcnt(0)+barrier)
            short8 af[4], bf[4];
#pragma unroll
            for (int fi = 0; fi < 4; ++fi) {
                int row = wy * 64 + 16 * fi + tx;
                int ph = g ^ ((row >> 2) & 3);
                af[fi] = *(const short8*)&Ab[row * 32 + ph * 8];
            }
#pragma unroll
            for (int fj = 0; fj < 4; ++fj) {
                int row = wx * 64 + 16 * fj + tx;
                int ph = g ^ ((row >> 2) & 3);
                bf[fj] = *(const short8*)&Bb[row * 32 + ph * 8];
            }

            // issue next step's staging into the other buffer; its loads stay
            // in flight under the MFMA cluster below.
            if (s < 127) stage(s + 1, par ^ 1);

#pragma unroll
            for (int fi = 0; fi < 4; ++fi)
#pragma unroll
                for (int fj = 0; fj < 4; ++fj)
                    acc[fi][fj] = __builtin_amdgcn_mfma_f32_16x16x32_bf16(
                        af[fi], bf[fj], acc[fi][fj], 0, 0, 0);

            if (kk == 15) {
                // chunk epilogue: fold scores into per-lane top-2 (register-only
                // + preloaded eev) — more latency cover for in-flight staging.
#pragma unroll
                for (int fj = 0; fj < 4; ++fj) {
                    int col = c0 + wx * 64 + 16 * fj + tx;
                    float ev = eev[fj];
#pragma unroll
                    for (int fi = 0; fi < 4; ++fi)
#pragma unroll
                        for (int r = 0; r < 4; ++r) {
                            float sc = fmaf(-2.0f, acc[fi][fj][r], ev);
                            const int slot = fi * 4 + r;
                            bool b1 = sc < v1[slot];
                            bool b2 = sc < v2[slot];
                            float ov = v1[slot]; int oi = i1[slot];
                            v1[slot] = b1 ? sc : ov;
                            i1[slot] = b1 ? col : oi;
                            v2[slot] = b1 ? ov : (b2 ? sc : v2[slot]);
                            i2[slot] = b1 ? oi : (b2 ? col : i2[slot]);
                        }
                }
            }

            // single drain+barrier per step: next buffer staged by all waves,
            // and all waves' frag reads of this buffer are done.
            asm volatile("s_waitcnt vmcnt(0)" ::: "memory");
            __builtin_amdgcn_s_barrier();
        }
    }

    // cross-lane: per row, approx-top-4 (exact top-2) over the wave's 64 cols.
    // Reduction arrays alias dead tile LDS (4 KiB each, within S's 32 KiB).
    float (*s_scr)[2][4] = reinterpret_cast<float (*)[2][4]>(&S[0][0][0]);
    int   (*s_idx)[2][4] = reinterpret_cast<int (*)[2][4]>(&S[0][1][0]);

#pragma unroll
    for (int fi = 0; fi < 4; ++fi) {
#pragma unroll
        for (int r = 0; r < 4; ++r) {
            const int slot = fi * 4 + r;
            float m0 = v1[slot], m1 = v2[slot], m2 = FLT_MAX, m3 = FLT_MAX;
            int   q0 = i1[slot], q1 = i2[slot], q2 = 0, q3 = 0;
#pragma unroll
            for (int off = 1; off <= 8; off <<= 1) {
                float o0 = __shfl_xor(m0, off), o1 = __shfl_xor(m1, off);
                float o2 = __shfl_xor(m2, off), o3 = __shfl_xor(m3, off);
                int   p0 = __shfl_xor(q0, off), p1 = __shfl_xor(q1, off);
                int   p2 = __shfl_xor(q2, off), p3 = __shfl_xor(q3, off);
                INS4(o0, p0); INS4(o1, p1); INS4(o2, p2); INS4(o3, p3);
            }
            if (tx == 0) {
                int row = wy * 64 + 16 * fi + 4 * g + r;
                s_scr[row][wx][0] = m0; s_scr[row][wx][1] = m1;
                s_scr[row][wx][2] = m2; s_scr[row][wx][3] = m3;
                s_idx[row][wx][0] = q0; s_idx[row][wx][1] = q1;
                s_idx[row][wx][2] = q2; s_idx[row][wx][3] = q3;
            }
        }
    }
    __syncthreads();
    if (tid < 128) {
        float m0 = s_scr[tid][0][0], m1 = s_scr[tid][0][1],
              m2 = s_scr[tid][0][2], m3 = s_scr[tid][0][3];
        int   q0 = s_idx[tid][0][0], q1 = s_idx[tid][0][1],
              q2 = s_idx[tid][0][2], q3 = s_idx[tid][0][3];
#pragma unroll
        for (int q = 0; q < 4; ++q) INS4(s_scr[tid][1][q], s_idx[tid][1][q]);
        int pt = n0 + tid;
        scr16[(hf * 4 + 0) * NPTS + pt] = m0; idx16[(hf * 4 + 0) * NPTS + pt] = q0;
        scr16[(hf * 4 + 1) * NPTS + pt] = m1; idx16[(hf * 4 + 1) * NPTS + pt] = q1;
        scr16[(hf * 4 + 2) * NPTS + pt] = m2; idx16[(hf * 4 + 2) * NPTS + pt] = q2;
        scr16[(hf * 4 + 3) * NPTS + pt] = m3; idx16[(hf * 4 + 3) * NPTS + pt] = q3;
    }
}

// ---------------------------------------------------------------------------
// merge the four quarters' top-4 into global screen top-4 per point
__global__ void merge16_kernel(const float* __restrict__ scr16, const int* __restrict__ idx16,
                               int* __restrict__ cand) {
    int n = blockIdx.x * 256 + threadIdx.x;
    float m0 = FLT_MAX, m1 = FLT_MAX, m2 = FLT_MAX, m3 = FLT_MAX;
    int   q0 = 0, q1 = 0, q2 = 0, q3 = 0;
#pragma unroll
    for (int c = 0; c < 16; ++c) {
        float s = scr16[c * NPTS + n];
        int   i = idx16[c * NPTS + n];
        INS4(s, i);
    }
    cand[0 * NPTS + n] = q0; cand[1 * NPTS + n] = q1;
    cand[2 * NPTS + n] = q2; cand[3 * NPTS + n] = q3;
}

// ---------------------------------------------------------------------------
// Final selection emulating numpy fp32 (verified passing — unchanged)
__global__ void rescore_kernel(const float* __restrict__ x, const float* __restrict__ emb,
                               const int* __restrict__ cand,
                               const float* __restrict__ xx_np,
                               const float* __restrict__ ee_np,
                               float* __restrict__ ind_f,
                               float* __restrict__ ncs, const float* __restrict__ decay_p) {
    int w = threadIdx.x >> 6, lane = threadIdx.x & 63;
    int n = blockIdx.x * 4 + w;
    float xxv = xx_np[n];
    float bestd = FLT_MAX; int bidx = 0x7fffffff;
#pragma unroll
    for (int c = 0; c < 4; ++c) {
        int k = cand[c * NPTS + n];
        double acc = 0.0;
#pragma unroll
        for (int i = 0; i < 8; ++i) {
            int d = lane + i * 64;
            acc += (double)emb[(size_t)k * D + d] * (double)x[(size_t)n * D + d];
        }
#pragma unroll
        for (int off = 32; off >= 1; off >>= 1) acc += __shfl_xor(acc, off);
        float mf = (float)acc;
        float t  = __fmul_rn(2.0f, mf);
        float u  = __fsub_rn(xxv, t);
        float dd = __fadd_rn(u, ee_np[k]);
        if (dd < bestd || (dd == bestd && k < bidx)) { bestd = dd; bidx = k; }
    }
    if (lane == 0) {
        ind_f[n] = (float)bidx;
        atomicAdd(&ncs[bidx], 1.0f - decay_p[0]);
    }
}

// ---------------------------------------------------------------------------
__global__ void gather_scatter_kernel(const float* __restrict__ x,
                                      const float* __restrict__ emb,
                                      const float* __restrict__ ind_f,
                                      float* __restrict__ quant, float* __restrict__ nea,
                                      const float* __restrict__ decay_p) {
    int gid = blockIdx.x * 256 + threadIdx.x;   // NPTS * (D/4)
    int n = gid >> 7, dq = gid & 127;
    int k = (int)ind_f[n];
    float4 e4 = *(const float4*)(emb + (size_t)k * D + dq * 4);
    *(float4*)(quant + (size_t)n * D + dq * 4) = e4;
    float4 x4 = *(const float4*)(x + (size_t)n * D + dq * 4);
    float wgt = 1.0f - decay_p[0];
    float* base = nea + (size_t)k * D + dq * 4;
    atomicAdd(base + 0, x4.x * wgt);
    atomicAdd(base + 1, x4.y * wgt);
    atomicAdd(base + 2, x4.z * wgt);
    atomicAdd(base + 3, x4.w * wgt);
}

// ---------------------------------------------------------------------------
__global__ void total_kernel(const float* __restrict__ ncs, float* __restrict__ total) {
    __shared__ float sd[1024];
    int t = threadIdx.x;
    sd[t] = ncs[t] + ncs[t + 1024] + ncs[t + 2048] + ncs[t + 3072];
    __syncthreads();
    for (int st = 512; st > 0; st >>= 1) {
        if (t < st) sd[t] += sd[t + st];
        __syncthreads();
    }
    if (t == 0) total[0] = sd[0];
}

__global__ void new_embed_kernel(const float* __restrict__ nea, const float* __restrict__ ncs,
                                 const float* __restrict__ total, float* __restrict__ ne) {
    int i = blockIdx.x * 256 + threadIdx.x;   // K*D
    int k = i >> 9;
    float t = total[0];
    float sm = (ncs[k] + EPSV) / (t + EPSV * (float)KCODES) * t;
    ne[i] = nea[i] / sm;
}

// ---------------------------------------------------------------------------
extern "C" void kernel_launch(void* const* d_in, const int* in_sizes, int n_in,
                              void* d_out, int out_size, void* d_ws, size_t ws_size,
                              hipStream_t stream) {
    const float* x     = (const float*)d_in[0];
    const float* emb   = (const float*)d_in[1];
    const float* cs    = (const float*)d_in[2];
    const float* ea    = (const float*)d_in[3];
    const float* decay = (const float*)d_in[4];

    float* out   = (float*)d_out;
    float* quant = out;                               // NPTS*D
    float* ind_f = out + (size_t)NPTS * D;            // NPTS
    float* ncs   = ind_f + NPTS;                      // KCODES
    float* nea   = ncs + KCODES;                      // KCODES*D
    float* ne    = nea + (size_t)KCODES * D;          // KCODES*D

    float* ws    = (float*)d_ws;
    float* ee_np = ws;                                // KCODES
    float* xx_np = ws + KCODES;                       // NPTS
    float* scr16 = xx_np + NPTS;                      // 16*NPTS
    int*   idx16 = (int*)(scr16 + 16 * (size_t)NPTS); // 16*NPTS
    int*   cand  = idx16 + 16 * (size_t)NPTS;         // 4*NPTS
    u16*   eb    = (u16*)(cand + 4 * (size_t)NPTS);   // KCODES*D bf16 (16B-aligned)
    float* total = (float*)(eb + (size_t)KCODES * D); // 1

    // bf16 x staged in the quant output region (overwritten at the end)
    u16* xb = (u16*)quant;

    hipLaunchKernelGGL(cvt_bf16_kernel, dim3(NPTS * D / 2048),   dim3(256), 0, stream, x, xb);
    hipLaunchKernelGGL(cvt_bf16_kernel, dim3(KCODES * D / 2048), dim3(256), 0, stream, emb, eb);
    hipLaunchKernelGGL(ee_np_kernel,    dim3(KCODES / 8),        dim3(256), 0, stream, emb, ee_np);
    hipLaunchKernelGGL(xx_np_kernel,    dim3(NPTS / 8),          dim3(256), 0, stream, x, xx_np);
    hipLaunchKernelGGL(init_kernel,     dim3(KCODES * (D / 256)), dim3(256), 0, stream, cs, ea, decay, ncs, nea);
    hipLaunchKernelGGL(screen_kernel,   dim3(NPTS / 128, 4),     dim3(256), 0, stream,
                       xb, eb, ee_np, scr16, idx16);
    hipLaunchKernelGGL(merge16_kernel,  dim3(NPTS / 256),        dim3(256), 0, stream, scr16, idx16, cand);
    hipLaunchKernelGGL(rescore_kernel,  dim3(NPTS / 4),          dim3(256), 0, stream,
                       x, emb, cand, xx_np, ee_np, ind_f, ncs, decay);
    hipLaunchKernelGGL(gather_scatter_kernel, dim3(NPTS * (D / 4) / 256), dim3(256), 0, stream,
                       x, emb, ind_f, quant, nea, decay);
    hipLaunchKernelGGL(total_kernel,    dim3(1),                 dim3(1024), 0, stream, ncs, total);
    hipLaunchKernelGGL(new_embed_kernel, dim3(KCODES * (D / 256)), dim3(256), 0, stream, nea, ncs, total, ne);
}

// Round 7
// 705.335 us; speedup vs baseline: 1.3192x; 1.0254x over previous
//
#include <hip/hip_runtime.h>
#include <float.h>

// Problem shape (fixed by setup_inputs): x[32768,512], embed[4096,512]
#define D 512
#define NPTS 32768
#define KCODES 4096
#define EPSV 1e-6f

typedef __attribute__((ext_vector_type(8))) short short8;
typedef __attribute__((ext_vector_type(4))) float f32x4;
typedef unsigned short u16;
typedef __attribute__((ext_vector_type(8))) unsigned short u16x8;

// ---------------------------------------------------------------------------
// async global->LDS, 16B per lane (dest = wave-uniform base + lane*16)
__device__ __forceinline__ void async16(void* lds, const void* gl) {
    __builtin_amdgcn_global_load_lds(
        (const __attribute__((address_space(1))) unsigned int*)gl,
        (__attribute__((address_space(3))) unsigned int*)lds,
        16, 0, 0);
}

// fp32 -> bf16 round-to-nearest-even
__device__ __forceinline__ unsigned short f2bf(float f) {
    unsigned int u = __float_as_uint(f);
    u += 0x7fffu + ((u >> 16) & 1u);
    return (unsigned short)(u >> 16);
}

__global__ void cvt_bf16_kernel(const float* __restrict__ in, u16* __restrict__ out) {
    size_t i = (size_t)(blockIdx.x * 256 + threadIdx.x) * 8;
    float4 a = *(const float4*)(in + i);
    float4 b = *(const float4*)(in + i + 4);
    u16x8 r = { f2bf(a.x), f2bf(a.y), f2bf(a.z), f2bf(a.w),
                f2bf(b.x), f2bf(b.y), f2bf(b.z), f2bf(b.w) };
    *(u16x8*)(out + i) = r;
}

// ---------------------------------------------------------------------------
// Bit-exact emulation of numpy fp32 pairwise sum of squares over a 512-row.
// (verified passing - do not change)
__device__ __forceinline__ float np_sumsq_512(const float* __restrict__ row, int l) {
    int b = l >> 3, j = l & 7;
    int base = b * 128 + j;
    float a = row[base];
    float r = __fmul_rn(a, a);
#pragma unroll
    for (int t = 1; t < 16; ++t) {
        float v = row[base + 8 * t];
        r = __fadd_rn(r, __fmul_rn(v, v));
    }
#pragma unroll
    for (int off = 1; off <= 16; off <<= 1)
        r = __fadd_rn(r, __shfl_xor(r, off));
    return r;
}

__global__ void xx_np_kernel(const float* __restrict__ x, float* __restrict__ xx_np) {
    int w = threadIdx.x >> 6, lane = threadIdx.x & 63;
    int hf = lane >> 5, l = lane & 31;
    int p = blockIdx.x * 8 + w * 2 + hf;
    float r = np_sumsq_512(x + (size_t)p * D, l);
    if (l == 0) xx_np[p] = r;
}

__global__ void ee_np_kernel(const float* __restrict__ emb, float* __restrict__ ee_np) {
    int w = threadIdx.x >> 6, lane = threadIdx.x & 63;
    int hf = lane >> 5, l = lane & 31;
    int k = blockIdx.x * 8 + w * 2 + hf;
    float r = np_sumsq_512(emb + (size_t)k * D, l);
    if (l == 0) ee_np[k] = r;
}

// ---------------------------------------------------------------------------
// fused EMA inits (one launch): nea = ea*decay over K*D; ncs = cs*decay over K
__global__ void init_kernel(const float* __restrict__ cs, const float* __restrict__ ea,
                            const float* __restrict__ decay_p,
                            float* __restrict__ ncs, float* __restrict__ nea) {
    int i = blockIdx.x * 256 + threadIdx.x;
    float dv = decay_p[0];
    nea[i] = ea[i] * dv;
    if (i < KCODES) ncs[i] = cs[i] * dv;
}

// ---------------------------------------------------------------------------
// bf16 MFMA screen: scores s[n][k] = ee[k] - 2*dot(x_n, e_k).
// Grid (NPTS/128, 4): block = 128 pts x 1024 codes (one code-quarter), 8
// chunks of 128 codes; emits approx-top-4 (exact top-2) per (point, quarter).
// K-loop: TRIPLE-buffered LDS, 2-steps-ahead staging, counted s_waitcnt
// vmcnt(4) per step (T4: never drain to 0 in the main loop). In-loop VMEM =
// exactly the 4 stage loads per step in strict FIFO order, so vmcnt(4) at
// step end drains stage(s+1) and leaves stage(s+2) in flight with ~2 full
// steps of latency cover. ee[] is staged to an LDS table before the loop so
// epilogue ee reads are lgkm (off the vmcnt FIFO).
// LDS chunk-XOR-swizzle p = kc ^ ((row>>2)&3) keeps frag ds_read_b128
// 2-way-per-bank (free, m136). ds_read per-lane offsets hoisted out of the
// K-loop (only the wave-uniform buffer base rotates -> SALU).
// __launch_bounds__(256, 2): live state ~190 regs/wave; forcing 4 blocks/CU
// (round 3) spilled to scratch (WRITE_SIZE 5.6MB -> 728MB). Keep 2.
#define INS4(s_, c_)  do {                                                  \
    bool l0 = (s_) < m0, l1 = (s_) < m1, l2 = (s_) < m2, l3 = (s_) < m3;    \
    m3 = l2 ? m2 : (l3 ? (s_) : m3);  q3 = l2 ? q2 : (l3 ? (c_) : q3);      \
    m2 = l1 ? m1 : (l2 ? (s_) : m2);  q2 = l1 ? q1 : (l2 ? (c_) : q2);      \
    m1 = l0 ? m0 : (l1 ? (s_) : m1);  q1 = l0 ? q0 : (l1 ? (c_) : q1);      \
    m0 = l0 ? (s_) : m0;              q0 = l0 ? (c_) : q0;                  \
} while (0)

__global__ __launch_bounds__(256, 2)
void screen_kernel(const u16* __restrict__ xb, const u16* __restrict__ eb,
                   const float* __restrict__ ee,
                   float* __restrict__ scr16, int* __restrict__ idx16) {
    // [buf 0..2][A/B][128 rows * 32 k] bf16 = 48 KiB; reduction arrays alias
    // buffer 0 after the K loop (dead by then). eeS: 4 KiB ee table.
    __shared__ __align__(16) u16 S[3][2][128 * 32];
    __shared__ float eeS[1024];

    const int tid = threadIdx.x;
    const int w = tid >> 6, lane = tid & 63;
    const int wy = w >> 1, wx = w & 1;
    const int tx = lane & 15, g = lane >> 4;
    const int n0 = blockIdx.x * 128;
    const int hf = blockIdx.y;                 // code quarter 0..3
    const int hbase = hf * 1024;

    // per-lane running top-2 per row-slot (fi*4+r)
    float v1[16], v2[16];
    int   i1[16], i2[16];
#pragma unroll
    for (int s = 0; s < 16; ++s) { v1[s] = FLT_MAX; v2[s] = FLT_MAX; i1[s] = 0; i2[s] = 0; }

    // hoisted per-lane ds_read element offsets (within one buffer's A/B region)
    int aoff[4], boff[4];
#pragma unroll
    for (int fi = 0; fi < 4; ++fi) {
        int row = wy * 64 + 16 * fi + tx;
        int ph = g ^ ((row >> 2) & 3);
        aoff[fi] = row * 32 + ph * 8;
    }
#pragma unroll
    for (int fj = 0; fj < 4; ++fj) {
        int row = wx * 64 + 16 * fj + tx;
        int ph = g ^ ((row >> 2) & 3);
        boff[fj] = 4096 + row * 32 + ph * 8;   // B region is +4096 elems
    }
    const int eoff = wx * 64 + tx;             // per-lane ee table offset

    // staging lane constants: instr t covers rows [16t,16t+16); lane l ->
    // row 16t+(l>>2), physical 16B-chunk l&3 holds logical chunk (l&3)^(l>>4)
    const int kc = (lane & 3) ^ (lane >> 4);
    const int srow = lane >> 2;
    const int ta = 2 * w, tb = 2 * w + 1;
    const size_t aoa = (size_t)(n0 + 16 * ta + srow) * D + kc * 8;
    const size_t aob = (size_t)(n0 + 16 * tb + srow) * D + kc * 8;
    const size_t boa = (size_t)(hbase + 16 * ta + srow) * D + kc * 8;
    const size_t bob = (size_t)(hbase + 16 * tb + srow) * D + kc * 8;

    auto stage = [&](int s, int p) {
        const int ch = s >> 4;
        const size_t ko = (size_t)((s & 15) * 32);
        const size_t co = (size_t)ch * (128 * D);
        async16(&S[p][0][ta * 512], xb + aoa + ko);
        async16(&S[p][0][tb * 512], xb + aob + ko);
        async16(&S[p][1][ta * 512], eb + boa + co + ko);
        async16(&S[p][1][tb * 512], eb + bob + co + ko);
    };

    // ee -> LDS table. Its global loads complete before the ds_writes (the
    // compiler inserts the wait), so they never sit in the staging vmcnt FIFO.
#pragma unroll
    for (int q = 0; q < 4; ++q) eeS[tid + 256 * q] = ee[hbase + tid + 256 * q];

    // prologue: fill buffers 0 and 1; drain buffer 0 only (counted wait).
    stage(0, 0);
    stage(1, 1);
    asm volatile("s_waitcnt vmcnt(4)" ::: "memory");
    __builtin_amdgcn_s_barrier();

    const u16* Sbase = &S[0][0][0];

    for (int c = 0; c < 8; ++c) {
        f32x4 acc[4][4];
#pragma unroll
        for (int fi = 0; fi < 4; ++fi)
#pragma unroll
            for (int fj = 0; fj < 4; ++fj) acc[fi][fj] = (f32x4){0.f, 0.f, 0.f, 0.f};

        for (int kk = 0; kk < 16; ++kk) {
            const int s = c * 16 + kk;
            const u16* bp = Sbase + (s % 3) * 8192;   // uniform base, SALU

            // ds_read current buffer (stage(s) drained at end of step s-1)
            short8 af[4], bf[4];
#pragma unroll
            for (int fi = 0; fi < 4; ++fi) af[fi] = *(const short8*)(bp + aoff[fi]);
#pragma unroll
            for (int fj = 0; fj < 4; ++fj) bf[fj] = *(const short8*)(bp + boff[fj]);

            // issue stage(s+2): stays in flight across ~2 full steps
            if (s < 126) stage(s + 2, (s + 2) % 3);

#pragma unroll
            for (int fi = 0; fi < 4; ++fi)
#pragma unroll
                for (int fj = 0; fj < 4; ++fj)
                    acc[fi][fj] = __builtin_amdgcn_mfma_f32_16x16x32_bf16(
                        af[fi], bf[fj], acc[fi][fj], 0, 0, 0);

            if (kk == 15) {
                // chunk epilogue: fold scores into per-lane top-2; ee via LDS
#pragma unroll
                for (int fj = 0; fj < 4; ++fj) {
                    int col = hbase + c * 128 + wx * 64 + 16 * fj + tx;
                    float ev = eeS[c * 128 + eoff + 16 * fj];
#pragma unroll
                    for (int fi = 0; fi < 4; ++fi)
#pragma unroll
                        for (int r = 0; r < 4; ++r) {
                            float sc = fmaf(-2.0f, acc[fi][fj][r], ev);
                            const int slot = fi * 4 + r;
                            bool b1 = sc < v1[slot];
                            bool b2 = sc < v2[slot];
                            float ov = v1[slot]; int oi = i1[slot];
                            v1[slot] = b1 ? sc : ov;
                            i1[slot] = b1 ? col : oi;
                            v2[slot] = b1 ? ov : (b2 ? sc : v2[slot]);
                            i2[slot] = b1 ? oi : (b2 ? col : i2[slot]);
                        }
                }
            }

            // counted wait: drain stage(s+1) only, keep stage(s+2) in flight.
            // Tail (s>=126): no deeper stages outstanding -> full drain.
            if (s < 126) { asm volatile("s_waitcnt vmcnt(4)" ::: "memory"); }
            else         { asm volatile("s_waitcnt vmcnt(0)" ::: "memory"); }
            __builtin_amdgcn_s_barrier();
        }
    }

    // cross-lane: per row, approx-top-4 (exact top-2) over the wave's 64 cols.
    // Reduction arrays alias dead tile LDS (within buffer 0's regions).
    float (*s_scr)[2][4] = reinterpret_cast<float (*)[2][4]>(&S[0][0][0]);
    int   (*s_idx)[2][4] = reinterpret_cast<int (*)[2][4]>(&S[0][1][0]);

#pragma unroll
    for (int fi = 0; fi < 4; ++fi) {
#pragma unroll
        for (int r = 0; r < 4; ++r) {
            const int slot = fi * 4 + r;
            float m0 = v1[slot], m1 = v2[slot], m2 = FLT_MAX, m3 = FLT_MAX;
            int   q0 = i1[slot], q1 = i2[slot], q2 = 0, q3 = 0;
#pragma unroll
            for (int off = 1; off <= 8; off <<= 1) {
                float o0 = __shfl_xor(m0, off), o1 = __shfl_xor(m1, off);
                float o2 = __shfl_xor(m2, off), o3 = __shfl_xor(m3, off);
                int   p0 = __shfl_xor(q0, off), p1 = __shfl_xor(q1, off);
                int   p2 = __shfl_xor(q2, off), p3 = __shfl_xor(q3, off);
                INS4(o0, p0); INS4(o1, p1); INS4(o2, p2); INS4(o3, p3);
            }
            if (tx == 0) {
                int row = wy * 64 + 16 * fi + 4 * g + r;
                s_scr[row][wx][0] = m0; s_scr[row][wx][1] = m1;
                s_scr[row][wx][2] = m2; s_scr[row][wx][3] = m3;
                s_idx[row][wx][0] = q0; s_idx[row][wx][1] = q1;
                s_idx[row][wx][2] = q2; s_idx[row][wx][3] = q3;
            }
        }
    }
    __syncthreads();
    if (tid < 128) {
        float m0 = s_scr[tid][0][0], m1 = s_scr[tid][0][1],
              m2 = s_scr[tid][0][2], m3 = s_scr[tid][0][3];
        int   q0 = s_idx[tid][0][0], q1 = s_idx[tid][0][1],
              q2 = s_idx[tid][0][2], q3 = s_idx[tid][0][3];
#pragma unroll
        for (int q = 0; q < 4; ++q) INS4(s_scr[tid][1][q], s_idx[tid][1][q]);
        int pt = n0 + tid;
        scr16[(hf * 4 + 0) * NPTS + pt] = m0; idx16[(hf * 4 + 0) * NPTS + pt] = q0;
        scr16[(hf * 4 + 1) * NPTS + pt] = m1; idx16[(hf * 4 + 1) * NPTS + pt] = q1;
        scr16[(hf * 4 + 2) * NPTS + pt] = m2; idx16[(hf * 4 + 2) * NPTS + pt] = q2;
        scr16[(hf * 4 + 3) * NPTS + pt] = m3; idx16[(hf * 4 + 3) * NPTS + pt] = q3;
    }
}

// ---------------------------------------------------------------------------
// merge the four quarters' top-4 into global screen top-4 per point
__global__ void merge16_kernel(const float* __restrict__ scr16, const int* __restrict__ idx16,
                               int* __restrict__ cand) {
    int n = blockIdx.x * 256 + threadIdx.x;
    float m0 = FLT_MAX, m1 = FLT_MAX, m2 = FLT_MAX, m3 = FLT_MAX;
    int   q0 = 0, q1 = 0, q2 = 0, q3 = 0;
#pragma unroll
    for (int c = 0; c < 16; ++c) {
        float s = scr16[c * NPTS + n];
        int   i = idx16[c * NPTS + n];
        INS4(s, i);
    }
    cand[0 * NPTS + n] = q0; cand[1 * NPTS + n] = q1;
    cand[2 * NPTS + n] = q2; cand[3 * NPTS + n] = q3;
}

// ---------------------------------------------------------------------------
// Final selection emulating numpy fp32 (verified passing - unchanged)
__global__ void rescore_kernel(const float* __restrict__ x, const float* __restrict__ emb,
                               const int* __restrict__ cand,
                               const float* __restrict__ xx_np,
                               const float* __restrict__ ee_np,
                               float* __restrict__ ind_f,
                               float* __restrict__ ncs, const float* __restrict__ decay_p) {
    int w = threadIdx.x >> 6, lane = threadIdx.x & 63;
    int n = blockIdx.x * 4 + w;
    float xxv = xx_np[n];
    float bestd = FLT_MAX; int bidx = 0x7fffffff;
#pragma unroll
    for (int c = 0; c < 4; ++c) {
        int k = cand[c * NPTS + n];
        double acc = 0.0;
#pragma unroll
        for (int i = 0; i < 8; ++i) {
            int d = lane + i * 64;
            acc += (double)emb[(size_t)k * D + d] * (double)x[(size_t)n * D + d];
        }
#pragma unroll
        for (int off = 32; off >= 1; off >>= 1) acc += __shfl_xor(acc, off);
        float mf = (float)acc;
        float t  = __fmul_rn(2.0f, mf);
        float u  = __fsub_rn(xxv, t);
        float dd = __fadd_rn(u, ee_np[k]);
        if (dd < bestd || (dd == bestd && k < bidx)) { bestd = dd; bidx = k; }
    }
    if (lane == 0) {
        ind_f[n] = (float)bidx;
        atomicAdd(&ncs[bidx], 1.0f - decay_p[0]);
    }
}

// ---------------------------------------------------------------------------
__global__ void gather_scatter_kernel(const float* __restrict__ x,
                                      const float* __restrict__ emb,
                                      const float* __restrict__ ind_f,
                                      float* __restrict__ quant, float* __restrict__ nea,
                                      const float* __restrict__ decay_p) {
    int gid = blockIdx.x * 256 + threadIdx.x;   // NPTS * (D/4)
    int n = gid >> 7, dq = gid & 127;
    int k = (int)ind_f[n];
    float4 e4 = *(const float4*)(emb + (size_t)k * D + dq * 4);
    *(float4*)(quant + (size_t)n * D + dq * 4) = e4;
    float4 x4 = *(const float4*)(x + (size_t)n * D + dq * 4);
    float wgt = 1.0f - decay_p[0];
    float* base = nea + (size_t)k * D + dq * 4;
    atomicAdd(base + 0, x4.x * wgt);
    atomicAdd(base + 1, x4.y * wgt);
    atomicAdd(base + 2, x4.z * wgt);
    atomicAdd(base + 3, x4.w * wgt);
}

// ---------------------------------------------------------------------------
__global__ void total_kernel(const float* __restrict__ ncs, float* __restrict__ total) {
    __shared__ float sd[1024];
    int t = threadIdx.x;
    sd[t] = ncs[t] + ncs[t + 1024] + ncs[t + 2048] + ncs[t + 3072];
    __syncthreads();
    for (int st = 512; st > 0; st >>= 1) {
        if (t < st) sd[t] += sd[t + st];
        __syncthreads();
    }
    if (t == 0) total[0] = sd[0];
}

__global__ void new_embed_kernel(const float* __restrict__ nea, const float* __restrict__ ncs,
                                 const float* __restrict__ total, float* __restrict__ ne) {
    int i = blockIdx.x * 256 + threadIdx.x;   // K*D
    int k = i >> 9;
    float t = total[0];
    float sm = (ncs[k] + EPSV) / (t + EPSV * (float)KCODES) * t;
    ne[i] = nea[i] / sm;
}

// ---------------------------------------------------------------------------
extern "C" void kernel_launch(void* const* d_in, const int* in_sizes, int n_in,
                              void* d_out, int out_size, void* d_ws, size_t ws_size,
                              hipStream_t stream) {
    const float* x     = (const float*)d_in[0];
    const float* emb   = (const float*)d_in[1];
    const float* cs    = (const float*)d_in[2];
    const float* ea    = (const float*)d_in[3];
    const float* decay = (const float*)d_in[4];

    float* out   = (float*)d_out;
    float* quant = out;                               // NPTS*D
    float* ind_f = out + (size_t)NPTS * D;            // NPTS
    float* ncs   = ind_f + NPTS;                      // KCODES
    float* nea   = ncs + KCODES;                      // KCODES*D
    float* ne    = nea + (size_t)KCODES * D;          // KCODES*D

    float* ws    = (float*)d_ws;
    float* ee_np = ws;                                // KCODES
    float* xx_np = ws + KCODES;                       // NPTS
    float* scr16 = xx_np + NPTS;                      // 16*NPTS
    int*   idx16 = (int*)(scr16 + 16 * (size_t)NPTS); // 16*NPTS
    int*   cand  = idx16 + 16 * (size_t)NPTS;         // 4*NPTS
    u16*   eb    = (u16*)(cand + 4 * (size_t)NPTS);   // KCODES*D bf16 (16B-aligned)
    float* total = (float*)(eb + (size_t)KCODES * D); // 1

    // bf16 x staged in the quant output region (overwritten at the end)
    u16* xb = (u16*)quant;

    hipLaunchKernelGGL(cvt_bf16_kernel, dim3(NPTS * D / 2048),   dim3(256), 0, stream, x, xb);
    hipLaunchKernelGGL(cvt_bf16_kernel, dim3(KCODES * D / 2048), dim3(256), 0, stream, emb, eb);
    hipLaunchKernelGGL(ee_np_kernel,    dim3(KCODES / 8),        dim3(256), 0, stream, emb, ee_np);
    hipLaunchKernelGGL(xx_np_kernel,    dim3(NPTS / 8),          dim3(256), 0, stream, x, xx_np);
    hipLaunchKernelGGL(init_kernel,     dim3(KCODES * (D / 256)), dim3(256), 0, stream, cs, ea, decay, ncs, nea);
    hipLaunchKernelGGL(screen_kernel,   dim3(NPTS / 128, 4),     dim3(256), 0, stream,
                       xb, eb, ee_np, scr16, idx16);
    hipLaunchKernelGGL(merge16_kernel,  dim3(NPTS / 256),        dim3(256), 0, stream, scr16, idx16, cand);
    hipLaunchKernelGGL(rescore_kernel,  dim3(NPTS / 4),          dim3(256), 0, stream,
                       x, emb, cand, xx_np, ee_np, ind_f, ncs, decay);
    hipLaunchKernelGGL(gather_scatter_kernel, dim3(NPTS * (D / 4) / 256), dim3(256), 0, stream,
                       x, emb, ind_f, quant, nea, decay);
    hipLaunchKernelGGL(total_kernel,    dim3(1),                 dim3(1024), 0, stream, ncs, total);
    hipLaunchKernelGGL(new_embed_kernel, dim3(KCODES * (D / 256)), dim3(256), 0, stream, nea, ncs, total, ne);
}